// Round 4
// baseline (456.083 us; speedup 1.0000x reference)
//
#include <hip/hip_runtime.h>
#include <math.h>
#include <stdint.h>

// Problem constants (B=2, T=2048, D=2048, N=16 q-heads, K=8 kv-heads, G=2, H=128)
// Inputs/outputs are FLOAT32; positions int32; mask bool (unused: causal).
// Internals bf16 (MFMA) with f32 accumulation.
//
// Workspace layout (u16 elements), total 75,497,472 bytes:
//   wq_t   [16][128][2048]   @ 0              (bf16, transposed)
//   wkv_t  [16][128][2048]   @ 4194304        (heads 0..7 = K, 8..15 = V)
//   wout_t [2048][2048]      @ 8388608
//   q      [2][16][2048][128]@ 12582912       (roped+scaled, bf16)
//   k      [2][8][2048][128] @ 20971520       (roped, bf16)
//   vt     [2][8][128][2048] @ 25165824       (V transposed: [h][t], bf16)
//   enc    [2][2048][16][128]@ 29360128       (bf16) -- aliased as xb before attn

typedef unsigned short u16;
using bf16x8 = __attribute__((ext_vector_type(8))) short;
using f32x4  = __attribute__((ext_vector_type(4))) float;

#define MFMA_BF16(a,b,c) __builtin_amdgcn_mfma_f32_16x16x32_bf16((a),(b),(c),0,0,0)

static __device__ __forceinline__ float b2f(u16 u) {
  union { unsigned int i; float f; } v; v.i = ((unsigned int)u) << 16; return v.f;
}
static __device__ __forceinline__ u16 f2b(float f) {
  union { float f; unsigned int i; } v; v.f = f;
  unsigned int r = v.i + 0x7fffu + ((v.i >> 16) & 1u);
  return (u16)(r >> 16);
}
// pack two f32 -> bf16x2 dword (round-half-up; inputs are >= 0 softmax weights)
static __device__ __forceinline__ unsigned pk2(float x0, float x1) {
  union { float f; unsigned u; } a, b;
  a.f = x0; b.f = x1;
  return __builtin_amdgcn_perm(b.u + 0x8000u, a.u + 0x8000u, 0x07060302u);
}
static __device__ __forceinline__ void gload_lds16(const void* g, void* l) {
  __builtin_amdgcn_global_load_lds((__attribute__((address_space(1))) void*)(g),
                                   (__attribute__((address_space(3))) void*)(l),
                                   16, 0, 0);
}

// ---------------- f32 -> bf16 bulk convert ----------------
__global__ __launch_bounds__(256) void f32_to_bf16(const float* __restrict__ src,
                                                   u16* __restrict__ dst, int n) {
  const int i = (blockIdx.x * 256 + threadIdx.x) * 4;
  if (i < n) {
    const float4 v = *(const float4*)(src + i);
    ushort4 o;
    o.x = f2b(v.x); o.y = f2b(v.y); o.z = f2b(v.z); o.w = f2b(v.w);
    *(ushort4*)(dst + i) = o;
  }
}

// ---------------- batched transpose f32 [rows][cols] -> bf16 [cols][rows] ----------------
__global__ __launch_bounds__(256) void transpose_f32_bf16(const float* __restrict__ src,
                                                          u16* __restrict__ dst,
                                                          int rows, int cols) {
  __shared__ u16 tile[32][33];
  const int c0 = blockIdx.x * 32;
  const int r0 = blockIdx.y * 32;
  const size_t matoff = (size_t)blockIdx.z * (size_t)rows * (size_t)cols;
  const float* s = src + matoff;
  u16* d = dst + matoff;
  const int tx = threadIdx.x, ty = threadIdx.y;
#pragma unroll
  for (int j = 0; j < 4; ++j)
    tile[ty + j * 8][tx] = f2b(s[(size_t)(r0 + ty + j * 8) * cols + (c0 + tx)]);
  __syncthreads();
#pragma unroll
  for (int j = 0; j < 4; ++j)
    d[(size_t)(c0 + ty + j * 8) * rows + (r0 + tx)] = tile[tx][ty + j * 8];
}

// ---------------- QKV projection GEMM ----------------
__global__ __launch_bounds__(256) void gemm_qkv(const u16* __restrict__ X,
                                                const u16* __restrict__ wqt,
                                                const u16* __restrict__ wkvt,
                                                u16* __restrict__ qb,
                                                u16* __restrict__ kb,
                                                u16* __restrict__ vtb) {
  __shared__ __align__(16) u16 sA[128 * 32];
  __shared__ __align__(16) u16 sB[128 * 32];
  const int m0 = blockIdx.x * 128;
  const int ct = blockIdx.y;
  const u16* Bt = (ct < 16) ? (wqt + (size_t)ct * 128 * 2048)
                            : (wkvt + (size_t)(ct - 16) * 128 * 2048);
  const int tid = threadIdx.x;
  const int wave = tid >> 6, lane = tid & 63;
  const int wm = wave & 1, wn = wave >> 1;
  const int quad = lane >> 4, l16 = lane & 15;
  const int srow = lane >> 2, sch = lane & 3;

  f32x4 acc[4][4] = {};

  for (int k0 = 0; k0 < 2048; k0 += 32) {
#pragma unroll
    for (int s = 0; s < 2; ++s) {
      const int instr = wave * 2 + s;
      const int row = instr * 16 + srow;
      gload_lds16(X + (size_t)(m0 + row) * 2048 + k0 + sch * 8, (char*)sA + instr * 1024);
      gload_lds16(Bt + (size_t)row * 2048 + k0 + sch * 8, (char*)sB + instr * 1024);
    }
    __syncthreads();
    bf16x8 af[4], bfr[4];
#pragma unroll
    for (int mf = 0; mf < 4; ++mf)
      af[mf] = *(const bf16x8*)(sA + (wm * 64 + mf * 16 + l16) * 32 + quad * 8);
#pragma unroll
    for (int nf = 0; nf < 4; ++nf)
      bfr[nf] = *(const bf16x8*)(sB + (wn * 64 + nf * 16 + l16) * 32 + quad * 8);
#pragma unroll
    for (int mf = 0; mf < 4; ++mf)
#pragma unroll
      for (int nf = 0; nf < 4; ++nf)
        acc[mf][nf] = MFMA_BF16(af[mf], bfr[nf], acc[mf][nf]);
    __syncthreads();
  }

#pragma unroll
  for (int mf = 0; mf < 4; ++mf) {
    const int mm = m0 + wm * 64 + mf * 16 + quad * 4;
    const int b = mm >> 11;
    const int t = mm & 2047;
#pragma unroll
    for (int nf = 0; nf < 4; ++nf) {
      const int h = wn * 64 + nf * 16 + l16;
      if (ct < 16) {
        u16* d = qb + (((size_t)b * 16 + ct) * 2048 + t) * 128 + h;
#pragma unroll
        for (int i = 0; i < 4; ++i) d[(size_t)i * 128] = f2b(acc[mf][nf][i]);
      } else if (ct < 24) {
        u16* d = kb + (((size_t)b * 8 + (ct - 16)) * 2048 + t) * 128 + h;
#pragma unroll
        for (int i = 0; i < 4; ++i) d[(size_t)i * 128] = f2b(acc[mf][nf][i]);
      } else {
        u16* d = vtb + (((size_t)b * 8 + (ct - 24)) * 128 + h) * 2048 + t;
        uint2 pkv;
        pkv.x = (unsigned)f2b(acc[mf][nf][0]) | ((unsigned)f2b(acc[mf][nf][1]) << 16);
        pkv.y = (unsigned)f2b(acc[mf][nf][2]) | ((unsigned)f2b(acc[mf][nf][3]) << 16);
        *(uint2*)d = pkv;
      }
    }
  }
}

// ---------------- RoPE (in-place on q and k, bf16) ----------------
__global__ __launch_bounds__(256) void rope_kernel(u16* __restrict__ qb,
                                                   u16* __restrict__ kb,
                                                   const int* __restrict__ pos) {
  const size_t idx = (size_t)blockIdx.x * 256 + threadIdx.x;
  const size_t QP = (size_t)1 << 22;
  u16* p;
  float scale;
  int b, t, j;
  if (idx < QP) {
    j = (int)(idx & 63); t = (int)((idx >> 6) & 2047);
    const int hd = (int)((idx >> 17) & 15); b = (int)(idx >> 21);
    p = qb + (((size_t)b * 16 + hd) * 2048 + t) * 128;
    scale = 0.08838834764831845f;
  } else {
    const size_t r = idx - QP;
    j = (int)(r & 63); t = (int)((r >> 6) & 2047);
    const int hd = (int)((r >> 17) & 7); b = (int)(r >> 20);
    p = kb + (((size_t)b * 8 + hd) * 2048 + t) * 128;
    scale = 1.0f;
  }
  const float fpos = (float)pos[(size_t)b * 2048 + t];
  const float ts = __powf(10000.0f, (float)j * (1.0f / 64.0f));
  const float ang = fpos / ts;
  float sn, cs;
  sincosf(ang, &sn, &cs);
  const float a = b2f(p[j]);
  const float c2 = b2f(p[j + 64]);
  p[j] = f2b((a * cs - c2 * sn) * scale);
  p[j + 64] = f2b((c2 * cs + a * sn) * scale);
}

// ---------------- fused causal attention, S^T formulation ----------------
// 1024 blocks x 256 thr. Block = one 64-row q-tile; Q descending with launch order
// (heavy blocks dispatch first, light blocks backfill). Wave owns 16 t.
// No P LDS round-trip (ds_bpermute). 4 blocks/CU resident (32KB LDS, <=128 VGPR).
__global__ __launch_bounds__(256, 4) void attn_fused(const u16* __restrict__ qg,
                                                     const u16* __restrict__ kg,
                                                     const u16* __restrict__ vtg,
                                                     u16* __restrict__ enc) {
  __shared__ __align__(16) char lds[32768];
  char* sK = lds;            // [64 s][128 h] bf16, 16B chunks swizzled: ch ^ (row&15)
  char* sV = lds + 16384;    // [128 h][64 s] bf16, 16B chunks swizzled: ch ^ (row&7)

  const int bid = blockIdx.x;
  const int head = bid & 31;           // heads interleaved at each Q
  const int Q = 31 - (bid >> 5);       // Q=31 (32 iters) first
  const int b = head >> 4;
  const int n = head & 15;
  const int kh = n >> 1;

  const u16* qbase = qg + ((size_t)b * 16 + n) * 2048 * 128;
  const u16* kbase = kg + ((size_t)b * 8 + kh) * 2048 * 128;
  const u16* vbase = vtg + ((size_t)b * 8 + kh) * 128 * 2048;

  const int tid = threadIdx.x, wave = tid >> 6, lane = tid & 63;
  const int quad = lane >> 4, l16 = lane & 15;
  const int bp_a0 = ((quad & 1) * 32 + l16) * 4;  // ds_bpermute byte idx, source lane S0
  const int bp_a1 = bp_a0 + 64;                   // source lane S1

  const int tw = Q * 64 + wave * 16;
  const int tlane = tw + l16;

  // Q B-fragments (n = l16 = t, k contiguous)
  bf16x8 qf[4];
#pragma unroll
  for (int kf = 0; kf < 4; ++kf)
    qf[kf] = *(const bf16x8*)(qbase + (size_t)tlane * 128 + kf * 32 + quad * 8);

  f32x4 o[8] = {};
  float mstate = -INFINITY, lstate = 0.0f;
  const float L2E = 1.4426950408889634f;
  // 50*tanh(x/50) = x*(1 - a1*u + a2*u^2 - a3*u^3), u = x^2  (Taylor, |x|<~25)
  const float A1 = 1.3333333333e-4f;   // 1/(3*2500)
  const float A2 = 2.1333333333e-8f;   // 2/(15*2500^2)
  const float A3 = 3.4539682540e-12f;  // 17/(315*2500^3)

#pragma unroll 1
  for (int si = 0; si <= Q; ++si) {
    const int s0 = si * 64;
    __syncthreads();
    // stage K (16KB) + V^T (16KB); coalesced float4 reads, swizzled LDS writes
#pragma unroll
    for (int r2 = 0; r2 < 4; ++r2) {
      const int idx = r2 * 256 + tid;
      const int kr = idx >> 4, kc = idx & 15;
      *(float4*)(sK + kr * 256 + ((kc ^ (kr & 15)) << 4)) =
          *(const float4*)(kbase + (size_t)(s0 + kr) * 128 + kc * 8);
      const int vr = idx >> 3, vc = idx & 7;
      *(float4*)(sV + vr * 128 + ((vc ^ (vr & 7)) << 4)) =
          *(const float4*)(vbase + (size_t)vr * 2048 + s0 + vc * 8);
    }
    __syncthreads();

    const bool diag = (si == Q);
    const int nfmax = diag ? wave : 3;        // skip fully-masked s-frags
    const int kmax = diag ? (wave >> 1) : 1;

    // S^T = K Q^T : A = K (m=s), B = Q (n=t). C: col=t=l16, row=s=quad*4+reg
    f32x4 sacc[4];
#pragma unroll
    for (int nf = 0; nf < 4; ++nf) {
      if (nf <= nfmax) {
        const int sr = nf * 16 + l16;
        f32x4 a = {0.f, 0.f, 0.f, 0.f};
#pragma unroll
        for (int kf = 0; kf < 4; ++kf) {
          const bf16x8 kfr =
              *(const bf16x8*)(sK + sr * 256 + (((kf * 4 + quad) ^ (sr & 15)) << 4));
          a = MFMA_BF16(kfr, qf[kf], a);
        }
        sacc[nf] = a;
      }
    }

    // poly softcap (vectorized) + mask + online softmax (per-lane column t)
    float mx = mstate;
#pragma unroll
    for (int nf = 0; nf < 4; ++nf) {
      if (nf <= nfmax) {
        const f32x4 xv = sacc[nf];
        const f32x4 u = xv * xv;
        f32x4 t = u * (-A3) + A2;
        t = u * t + (-A1);
        t = u * t + 1.0f;
        f32x4 tc = xv * t;
        if (diag) {
#pragma unroll
          for (int i = 0; i < 4; ++i) {
            const int sg = s0 + nf * 16 + quad * 4 + i;
            if (sg > tlane) tc[i] = -2.3819763e38f;
          }
        }
        sacc[nf] = tc;
#pragma unroll
        for (int i = 0; i < 4; ++i) mx = fmaxf(mx, tc[i]);
      }
    }
    mx = fmaxf(mx, __shfl_xor(mx, 16));
    mx = fmaxf(mx, __shfl_xor(mx, 32));
    const float mxl = mx * L2E;
    const float alpha = exp2f(fmaf(mstate, L2E, -mxl));
    mstate = mx;
    float rs = 0.0f;
#pragma unroll
    for (int nf = 0; nf < 4; ++nf) {
      if (nf <= nfmax) {
#pragma unroll
        for (int i = 0; i < 4; ++i) {
          const float pv = exp2f(fmaf(sacc[nf][i], L2E, -mxl));
          sacc[nf][i] = pv;
          rs += pv;
        }
      }
    }
    rs += __shfl_xor(rs, 16);
    rs += __shfl_xor(rs, 32);
    lstate = lstate * alpha + rs;
#pragma unroll
    for (int nf = 0; nf < 8; ++nf) o[nf] *= alpha;

    // pack P columns to bf16x2 dwords (per-lane)
    unsigned pkd[4][2];
#pragma unroll
    for (int nf = 0; nf < 4; ++nf) {
      if (nf <= nfmax) {
        pkd[nf][0] = pk2(sacc[nf][0], sacc[nf][1]);
        pkd[nf][1] = pk2(sacc[nf][2], sacc[nf][3]);
      } else {
        pkd[nf][0] = 0u; pkd[nf][1] = 0u;
      }
    }

    // O^T += V^T P^T : per chunk c2 (k = s 32-wide), build P^T B-frag via bpermute
#pragma unroll
    for (int c2 = 0; c2 < 2; ++c2) {
      if (c2 <= kmax) {
        const int lo = (quad >> 1);  // selects nf = 2*c2 + (quad>>1)
        const int dA0 = __builtin_amdgcn_ds_bpermute(bp_a0, (int)pkd[2 * c2][0]);
        const int dB0 = __builtin_amdgcn_ds_bpermute(bp_a0, (int)pkd[2 * c2 + 1][0]);
        const int dA1 = __builtin_amdgcn_ds_bpermute(bp_a0, (int)pkd[2 * c2][1]);
        const int dB1 = __builtin_amdgcn_ds_bpermute(bp_a0, (int)pkd[2 * c2 + 1][1]);
        const int dA2 = __builtin_amdgcn_ds_bpermute(bp_a1, (int)pkd[2 * c2][0]);
        const int dB2 = __builtin_amdgcn_ds_bpermute(bp_a1, (int)pkd[2 * c2 + 1][0]);
        const int dA3 = __builtin_amdgcn_ds_bpermute(bp_a1, (int)pkd[2 * c2][1]);
        const int dB3 = __builtin_amdgcn_ds_bpermute(bp_a1, (int)pkd[2 * c2 + 1][1]);
        union { int d[4]; bf16x8 v; } pb;
        pb.d[0] = lo ? dB0 : dA0;
        pb.d[1] = lo ? dB1 : dA1;
        pb.d[2] = lo ? dB2 : dA2;
        pb.d[3] = lo ? dB3 : dA3;
#pragma unroll
        for (int nfo = 0; nfo < 8; ++nfo) {
          const int hr = nfo * 16 + l16;
          const bf16x8 vb =
              *(const bf16x8*)(sV + hr * 128 + (((c2 * 4 + quad) ^ (hr & 7)) << 4));
          o[nfo] = MFMA_BF16(vb, pb.v, o[nfo]);
        }
      }
    }
  }

  // epilogue: O^T col=t=l16, row h = nfo*16 + quad*4 + i -> enc[b][t][n][h]
  const float inv = 1.0f / lstate;
  u16* d = enc + (((size_t)b * 2048 + tlane) * 16 + n) * 128 + quad * 4;
#pragma unroll
  for (int nfo = 0; nfo < 8; ++nfo) {
    uint2 st;
    st.x = (unsigned)f2b(o[nfo][0] * inv) | ((unsigned)f2b(o[nfo][1] * inv) << 16);
    st.y = (unsigned)f2b(o[nfo][2] * inv) | ((unsigned)f2b(o[nfo][3] * inv) << 16);
    *(uint2*)(d + nfo * 16) = st;
  }
}

// ---------------- output projection GEMM (f32 output) ----------------
__global__ __launch_bounds__(256) void gemm_out(const u16* __restrict__ A,
                                                const u16* __restrict__ Bt,
                                                float* __restrict__ C) {
  __shared__ __align__(16) u16 sA[128 * 32];
  __shared__ __align__(16) u16 sB[128 * 32];
  const int m0 = blockIdx.x * 128;
  const int n0 = blockIdx.y * 128;
  const int tid = threadIdx.x;
  const int wave = tid >> 6, lane = tid & 63;
  const int wm = wave & 1, wn = wave >> 1;
  const int quad = lane >> 4, l16 = lane & 15;
  const int srow = lane >> 2, sch = lane & 3;

  f32x4 acc[4][4] = {};

  for (int k0 = 0; k0 < 2048; k0 += 32) {
#pragma unroll
    for (int s = 0; s < 2; ++s) {
      const int instr = wave * 2 + s;
      const int row = instr * 16 + srow;
      gload_lds16(A + (size_t)(m0 + row) * 2048 + k0 + sch * 8, (char*)sA + instr * 1024);
      gload_lds16(Bt + (size_t)(n0 + row) * 2048 + k0 + sch * 8, (char*)sB + instr * 1024);
    }
    __syncthreads();
    bf16x8 af[4], bfr[4];
#pragma unroll
    for (int mf = 0; mf < 4; ++mf)
      af[mf] = *(const bf16x8*)(sA + (wm * 64 + mf * 16 + l16) * 32 + quad * 8);
#pragma unroll
    for (int nf = 0; nf < 4; ++nf)
      bfr[nf] = *(const bf16x8*)(sB + (wn * 64 + nf * 16 + l16) * 32 + quad * 8);
#pragma unroll
    for (int mf = 0; mf < 4; ++mf)
#pragma unroll
      for (int nf = 0; nf < 4; ++nf)
        acc[mf][nf] = MFMA_BF16(af[mf], bfr[nf], acc[mf][nf]);
    __syncthreads();
  }

#pragma unroll
  for (int mf = 0; mf < 4; ++mf) {
    const int mm = m0 + wm * 64 + mf * 16 + quad * 4;
#pragma unroll
    for (int nf = 0; nf < 4; ++nf) {
      const int col = n0 + wn * 64 + nf * 16 + l16;
#pragma unroll
      for (int i = 0; i < 4; ++i) C[(size_t)(mm + i) * 2048 + col] = acc[mf][nf][i];
    }
  }
}

extern "C" void kernel_launch(void* const* d_in, const int* in_sizes, int n_in,
                              void* d_out, int out_size, void* d_ws, size_t ws_size,
                              hipStream_t stream) {
  (void)in_sizes; (void)n_in; (void)out_size; (void)ws_size;
  const float* x     = (const float*)d_in[0];
  const int*   posi  = (const int*)d_in[1];
  const float* w_q   = (const float*)d_in[3];
  const float* w_kv  = (const float*)d_in[4];
  const float* w_out = (const float*)d_in[5];
  float* out = (float*)d_out;

  u16* ws = (u16*)d_ws;
  u16* wqt   = ws;
  u16* wkvt  = ws + (size_t)4194304;
  u16* woutt = ws + (size_t)8388608;
  u16* qb    = ws + (size_t)12582912;
  u16* kb    = ws + (size_t)20971520;
  u16* vtb   = ws + (size_t)25165824;
  u16* encb  = ws + (size_t)29360128;
  u16* xb    = encb;  // alias: consumed by gemm_qkv before attn writes enc

  f32_to_bf16<<<8192, 256, 0, stream>>>(x, xb, 8388608);
  transpose_f32_bf16<<<dim3(4, 64, 16), dim3(32, 8, 1), 0, stream>>>(w_q, wqt, 2048, 128);
  transpose_f32_bf16<<<dim3(4, 64, 16), dim3(32, 8, 1), 0, stream>>>(w_kv, wkvt, 2048, 128);
  transpose_f32_bf16<<<dim3(64, 64, 1), dim3(32, 8, 1), 0, stream>>>(w_out, woutt, 2048, 2048);
  gemm_qkv<<<dim3(32, 32), 256, 0, stream>>>(xb, wqt, wkvt, qb, kb, vtb);
  rope_kernel<<<24576, 256, 0, stream>>>(qb, kb, posi);
  attn_fused<<<1024, 256, 0, stream>>>(qb, kb, vtb, encb);
  gemm_out<<<dim3(32, 16), 256, 0, stream>>>(encb, woutt, out);
}

// Round 5
// 407.262 us; speedup vs baseline: 1.1199x; 1.1199x over previous
//
#include <hip/hip_runtime.h>
#include <math.h>
#include <stdint.h>

// Problem constants (B=2, T=2048, D=2048, N=16 q-heads, K=8 kv-heads, G=2, H=128)
// Inputs/outputs are FLOAT32; positions int32; mask bool (unused: causal).
// Internals bf16 (MFMA) with f32 accumulation.
//
// Workspace layout (u16 elements), total 75,497,472 bytes:
//   wq_t   [16][128][2048]   @ 0              (bf16, transposed)
//   wkv_t  [16][128][2048]   @ 4194304        (heads 0..7 = K, 8..15 = V)
//   wout_t [2048][2048]      @ 8388608
//   q      [2][16][2048][128]@ 12582912       (roped+scaled, bf16)
//   k      [2][8][2048][128] @ 20971520       (roped, bf16)
//   vt     [2][8][128][2048] @ 25165824       (V transposed: [h][t], bf16)
//   enc    [2][2048][16][128]@ 29360128       (bf16) -- aliased as xb before attn

typedef unsigned short u16;
using bf16x8 = __attribute__((ext_vector_type(8))) short;
using f32x4  = __attribute__((ext_vector_type(4))) float;

#define MFMA_BF16(a,b,c) __builtin_amdgcn_mfma_f32_16x16x32_bf16((a),(b),(c),0,0,0)

static __device__ __forceinline__ float b2f(u16 u) {
  union { unsigned int i; float f; } v; v.i = ((unsigned int)u) << 16; return v.f;
}
static __device__ __forceinline__ u16 f2b(float f) {
  union { float f; unsigned int i; } v; v.f = f;
  unsigned int r = v.i + 0x7fffu + ((v.i >> 16) & 1u);
  return (u16)(r >> 16);
}
// pack two f32 -> bf16x2 dword (round-half-up; inputs are >= 0 softmax weights)
static __device__ __forceinline__ unsigned pk2(float x0, float x1) {
  union { float f; unsigned u; } a, b;
  a.f = x0; b.f = x1;
  return __builtin_amdgcn_perm(b.u + 0x8000u, a.u + 0x8000u, 0x07060302u);
}
static __device__ __forceinline__ void gload_lds16(const void* g, void* l) {
  __builtin_amdgcn_global_load_lds((__attribute__((address_space(1))) void*)(g),
                                   (__attribute__((address_space(3))) void*)(l),
                                   16, 0, 0);
}

// ---------------- f32 -> bf16 bulk convert ----------------
__global__ __launch_bounds__(256) void f32_to_bf16(const float* __restrict__ src,
                                                   u16* __restrict__ dst, int n) {
  const int i = (blockIdx.x * 256 + threadIdx.x) * 4;
  if (i < n) {
    const float4 v = *(const float4*)(src + i);
    ushort4 o;
    o.x = f2b(v.x); o.y = f2b(v.y); o.z = f2b(v.z); o.w = f2b(v.w);
    *(ushort4*)(dst + i) = o;
  }
}

// ---------------- batched transpose f32 [rows][cols] -> bf16 [cols][rows] ----------------
__global__ __launch_bounds__(256) void transpose_f32_bf16(const float* __restrict__ src,
                                                          u16* __restrict__ dst,
                                                          int rows, int cols) {
  __shared__ u16 tile[32][33];
  const int c0 = blockIdx.x * 32;
  const int r0 = blockIdx.y * 32;
  const size_t matoff = (size_t)blockIdx.z * (size_t)rows * (size_t)cols;
  const float* s = src + matoff;
  u16* d = dst + matoff;
  const int tx = threadIdx.x, ty = threadIdx.y;
#pragma unroll
  for (int j = 0; j < 4; ++j)
    tile[ty + j * 8][tx] = f2b(s[(size_t)(r0 + ty + j * 8) * cols + (c0 + tx)]);
  __syncthreads();
#pragma unroll
  for (int j = 0; j < 4; ++j)
    d[(size_t)(c0 + ty + j * 8) * rows + (r0 + tx)] = tile[tx][ty + j * 8];
}

// ---------------- QKV projection GEMM ----------------
__global__ __launch_bounds__(256) void gemm_qkv(const u16* __restrict__ X,
                                                const u16* __restrict__ wqt,
                                                const u16* __restrict__ wkvt,
                                                u16* __restrict__ qb,
                                                u16* __restrict__ kb,
                                                u16* __restrict__ vtb) {
  __shared__ __align__(16) u16 sA[128 * 32];
  __shared__ __align__(16) u16 sB[128 * 32];
  const int m0 = blockIdx.x * 128;
  const int ct = blockIdx.y;
  const u16* Bt = (ct < 16) ? (wqt + (size_t)ct * 128 * 2048)
                            : (wkvt + (size_t)(ct - 16) * 128 * 2048);
  const int tid = threadIdx.x;
  const int wave = tid >> 6, lane = tid & 63;
  const int wm = wave & 1, wn = wave >> 1;
  const int quad = lane >> 4, l16 = lane & 15;
  const int srow = lane >> 2, sch = lane & 3;

  f32x4 acc[4][4] = {};

  for (int k0 = 0; k0 < 2048; k0 += 32) {
#pragma unroll
    for (int s = 0; s < 2; ++s) {
      const int instr = wave * 2 + s;
      const int row = instr * 16 + srow;
      gload_lds16(X + (size_t)(m0 + row) * 2048 + k0 + sch * 8, (char*)sA + instr * 1024);
      gload_lds16(Bt + (size_t)row * 2048 + k0 + sch * 8, (char*)sB + instr * 1024);
    }
    __syncthreads();
    bf16x8 af[4], bfr[4];
#pragma unroll
    for (int mf = 0; mf < 4; ++mf)
      af[mf] = *(const bf16x8*)(sA + (wm * 64 + mf * 16 + l16) * 32 + quad * 8);
#pragma unroll
    for (int nf = 0; nf < 4; ++nf)
      bfr[nf] = *(const bf16x8*)(sB + (wn * 64 + nf * 16 + l16) * 32 + quad * 8);
#pragma unroll
    for (int mf = 0; mf < 4; ++mf)
#pragma unroll
      for (int nf = 0; nf < 4; ++nf)
        acc[mf][nf] = MFMA_BF16(af[mf], bfr[nf], acc[mf][nf]);
    __syncthreads();
  }

#pragma unroll
  for (int mf = 0; mf < 4; ++mf) {
    const int mm = m0 + wm * 64 + mf * 16 + quad * 4;
    const int b = mm >> 11;
    const int t = mm & 2047;
#pragma unroll
    for (int nf = 0; nf < 4; ++nf) {
      const int h = wn * 64 + nf * 16 + l16;
      if (ct < 16) {
        u16* d = qb + (((size_t)b * 16 + ct) * 2048 + t) * 128 + h;
#pragma unroll
        for (int i = 0; i < 4; ++i) d[(size_t)i * 128] = f2b(acc[mf][nf][i]);
      } else if (ct < 24) {
        u16* d = kb + (((size_t)b * 8 + (ct - 16)) * 2048 + t) * 128 + h;
#pragma unroll
        for (int i = 0; i < 4; ++i) d[(size_t)i * 128] = f2b(acc[mf][nf][i]);
      } else {
        u16* d = vtb + (((size_t)b * 8 + (ct - 24)) * 128 + h) * 2048 + t;
        uint2 pkv;
        pkv.x = (unsigned)f2b(acc[mf][nf][0]) | ((unsigned)f2b(acc[mf][nf][1]) << 16);
        pkv.y = (unsigned)f2b(acc[mf][nf][2]) | ((unsigned)f2b(acc[mf][nf][3]) << 16);
        *(uint2*)d = pkv;
      }
    }
  }
}

// ---------------- RoPE (in-place on q and k, bf16) ----------------
__global__ __launch_bounds__(256) void rope_kernel(u16* __restrict__ qb,
                                                   u16* __restrict__ kb,
                                                   const int* __restrict__ pos) {
  const size_t idx = (size_t)blockIdx.x * 256 + threadIdx.x;
  const size_t QP = (size_t)1 << 22;
  u16* p;
  float scale;
  int b, t, j;
  if (idx < QP) {
    j = (int)(idx & 63); t = (int)((idx >> 6) & 2047);
    const int hd = (int)((idx >> 17) & 15); b = (int)(idx >> 21);
    p = qb + (((size_t)b * 16 + hd) * 2048 + t) * 128;
    scale = 0.08838834764831845f;
  } else {
    const size_t r = idx - QP;
    j = (int)(r & 63); t = (int)((r >> 6) & 2047);
    const int hd = (int)((r >> 17) & 7); b = (int)(r >> 20);
    p = kb + (((size_t)b * 8 + hd) * 2048 + t) * 128;
    scale = 1.0f;
  }
  const float fpos = (float)pos[(size_t)b * 2048 + t];
  const float ts = __powf(10000.0f, (float)j * (1.0f / 64.0f));
  const float ang = fpos / ts;
  float sn, cs;
  sincosf(ang, &sn, &cs);
  const float a = b2f(p[j]);
  const float c2 = b2f(p[j + 64]);
  p[j] = f2b((a * cs - c2 * sn) * scale);
  p[j + 64] = f2b((c2 * cs + a * sn) * scale);
}

// ---------------- fused causal attention, S^T formulation ----------------
// 512 blocks x 256 thr. Block = (head, pair p): pass A q-tile Q=p, pass B Q=31-p
// (q-tiles of 64 rows; every block does exactly 33 s-iters of 64 s -> perfectly
// balanced, all 512 blocks co-resident at 2 blocks/CU). Wave owns 16 t.
// Softcap bounds logits to <=50 -> fixed-offset softmax (no running max, no
// O-rescale): p = exp2(tc*log2e - 50*log2e); l reduced once in epilogue.
__global__ __launch_bounds__(256) void attn_fused(const u16* __restrict__ qg,
                                                  const u16* __restrict__ kg,
                                                  const u16* __restrict__ vtg,
                                                  u16* __restrict__ enc) {
  __shared__ __align__(16) char lds[32768];
  char* sK = lds;            // [64 s][128 h] bf16, 16B chunks swizzled: ch ^ (row&15)
  char* sV = lds + 16384;    // [128 h][64 s] bf16, 16B chunks swizzled: ch ^ (row&7)

  const int bid = blockIdx.x;
  const int x = bid & 7;           // head % 8  -> XCD locality
  const int i6 = bid >> 3;
  const int p = i6 & 15;
  const int head = (i6 >> 4) * 8 + x;
  const int b = head >> 4;
  const int n = head & 15;
  const int kh = n >> 1;

  const u16* qbase = qg + ((size_t)b * 16 + n) * 2048 * 128;
  const u16* kbase = kg + ((size_t)b * 8 + kh) * 2048 * 128;
  const u16* vbase = vtg + ((size_t)b * 8 + kh) * 128 * 2048;

  const int tid = threadIdx.x, wave = tid >> 6, lane = tid & 63;
  const int quad = lane >> 4, l16 = lane & 15;
  const int bp_a0 = ((quad & 1) * 32 + l16) * 4;  // ds_bpermute byte idx, source lane S0
  const int bp_a1 = bp_a0 + 64;                   // source lane S1

  const float L2E = 1.4426950408889634f;
  const float C50 = 72.13475204444817f;  // 50 * log2(e)
  // 50*tanh(x/50) = x*(1 - a1*u + a2*u^2 - a3*u^3), u = x^2  (Taylor, |x|<~25)
  const float A1 = 1.3333333333e-4f;
  const float A2 = 2.1333333333e-8f;
  const float A3 = 3.4539682540e-12f;

#pragma unroll 1
  for (int pass = 0; pass < 2; ++pass) {
    const int Q = pass ? (31 - p) : p;
    const int tw = Q * 64 + wave * 16;   // wave's t = tw + l16
    const int tlane = tw + l16;

    // Q B-fragments (n = l16 = t, k contiguous)
    bf16x8 qf[4];
#pragma unroll
    for (int kf = 0; kf < 4; ++kf)
      qf[kf] = *(const bf16x8*)(qbase + (size_t)tlane * 128 + kf * 32 + quad * 8);

    f32x4 o[8] = {};
    f32x4 lacc = {0.f, 0.f, 0.f, 0.f};

#pragma unroll 1
    for (int si = 0; si <= Q; ++si) {
      const int s0 = si * 64;
      __syncthreads();
      // stage K (16KB) + V^T (16KB); coalesced float4 reads, swizzled LDS writes
#pragma unroll
      for (int r2 = 0; r2 < 4; ++r2) {
        const int idx = r2 * 256 + tid;
        const int kr = idx >> 4, kc = idx & 15;
        *(float4*)(sK + kr * 256 + ((kc ^ (kr & 15)) << 4)) =
            *(const float4*)(kbase + (size_t)(s0 + kr) * 128 + kc * 8);
        const int vr = idx >> 3, vc = idx & 7;
        *(float4*)(sV + vr * 128 + ((vc ^ (vr & 7)) << 4)) =
            *(const float4*)(vbase + (size_t)vr * 2048 + s0 + vc * 8);
      }
      __syncthreads();

      const bool diag = (si == Q);
      const int nfmax = diag ? wave : 3;        // skip fully-masked s-frags
      const int kmax = diag ? (wave >> 1) : 1;

      // S^T = K Q^T : A = K (m=s), B = Q (n=t). C: col=t=l16, row=s=quad*4+reg
      f32x4 sacc[4];
#pragma unroll
      for (int nf = 0; nf < 4; ++nf) {
        if (nf <= nfmax) {
          const int sr = nf * 16 + l16;
          f32x4 a = {0.f, 0.f, 0.f, 0.f};
#pragma unroll
          for (int kf = 0; kf < 4; ++kf) {
            const bf16x8 kfr =
                *(const bf16x8*)(sK + sr * 256 + (((kf * 4 + quad) ^ (sr & 15)) << 4));
            a = MFMA_BF16(kfr, qf[kf], a);
          }
          sacc[nf] = a;
        }
      }

      // poly softcap + fixed-offset exp (no max, no rescale) + mask + l accumulate
#pragma unroll
      for (int nf = 0; nf < 4; ++nf) {
        if (nf <= nfmax) {
          const f32x4 xv = sacc[nf];
          const f32x4 u = xv * xv;
          f32x4 t = u * (-A3) + A2;
          t = u * t + (-A1);
          t = u * t + 1.0f;
          const f32x4 tc = xv * t;          // 50*tanh(x/50), in [-50, 50]
          f32x4 pv;
#pragma unroll
          for (int i = 0; i < 4; ++i) pv[i] = exp2f(fmaf(tc[i], L2E, -C50));
          if (diag) {
#pragma unroll
            for (int i = 0; i < 4; ++i) {
              const int sg = s0 + nf * 16 + quad * 4 + i;
              if (sg > tlane) pv[i] = 0.0f;
            }
          }
          sacc[nf] = pv;
          lacc += pv;
        }
      }

      // pack P columns to bf16x2 dwords (per-lane)
      unsigned pkd[4][2];
#pragma unroll
      for (int nf = 0; nf < 4; ++nf) {
        if (nf <= nfmax) {
          pkd[nf][0] = pk2(sacc[nf][0], sacc[nf][1]);
          pkd[nf][1] = pk2(sacc[nf][2], sacc[nf][3]);
        } else {
          pkd[nf][0] = 0u; pkd[nf][1] = 0u;
        }
      }

      // O^T += V^T P^T : per chunk c2 (k = s 32-wide), build P^T B-frag via bpermute
#pragma unroll
      for (int c2 = 0; c2 < 2; ++c2) {
        if (c2 <= kmax) {
          const int lo = (quad >> 1);  // selects nf = 2*c2 + (quad>>1)
          const int dA0 = __builtin_amdgcn_ds_bpermute(bp_a0, (int)pkd[2 * c2][0]);
          const int dB0 = __builtin_amdgcn_ds_bpermute(bp_a0, (int)pkd[2 * c2 + 1][0]);
          const int dA1 = __builtin_amdgcn_ds_bpermute(bp_a0, (int)pkd[2 * c2][1]);
          const int dB1 = __builtin_amdgcn_ds_bpermute(bp_a0, (int)pkd[2 * c2 + 1][1]);
          const int dA2 = __builtin_amdgcn_ds_bpermute(bp_a1, (int)pkd[2 * c2][0]);
          const int dB2 = __builtin_amdgcn_ds_bpermute(bp_a1, (int)pkd[2 * c2 + 1][0]);
          const int dA3 = __builtin_amdgcn_ds_bpermute(bp_a1, (int)pkd[2 * c2][1]);
          const int dB3 = __builtin_amdgcn_ds_bpermute(bp_a1, (int)pkd[2 * c2 + 1][1]);
          union { int d[4]; bf16x8 v; } pb;
          pb.d[0] = lo ? dB0 : dA0;
          pb.d[1] = lo ? dB1 : dA1;
          pb.d[2] = lo ? dB2 : dA2;
          pb.d[3] = lo ? dB3 : dA3;
#pragma unroll
          for (int nfo = 0; nfo < 8; ++nfo) {
            const int hr = nfo * 16 + l16;
            const bf16x8 vb =
                *(const bf16x8*)(sV + hr * 128 + (((c2 * 4 + quad) ^ (hr & 7)) << 4));
            o[nfo] = MFMA_BF16(vb, pb.v, o[nfo]);
          }
        }
      }
    }

    // epilogue: reduce l across quads (same t = l16 in each 16-lane group)
    float lsum = lacc[0] + lacc[1] + lacc[2] + lacc[3];
    lsum += __shfl_xor(lsum, 16);
    lsum += __shfl_xor(lsum, 32);
    const float inv = 1.0f / lsum;
    u16* d = enc + (((size_t)b * 2048 + tlane) * 16 + n) * 128 + quad * 4;
#pragma unroll
    for (int nfo = 0; nfo < 8; ++nfo) {
      uint2 st;
      st.x = (unsigned)f2b(o[nfo][0] * inv) | ((unsigned)f2b(o[nfo][1] * inv) << 16);
      st.y = (unsigned)f2b(o[nfo][2] * inv) | ((unsigned)f2b(o[nfo][3] * inv) << 16);
      *(uint2*)(d + nfo * 16) = st;
    }
  }
}

// ---------------- output projection GEMM (f32 output) ----------------
__global__ __launch_bounds__(256) void gemm_out(const u16* __restrict__ A,
                                                const u16* __restrict__ Bt,
                                                float* __restrict__ C) {
  __shared__ __align__(16) u16 sA[128 * 32];
  __shared__ __align__(16) u16 sB[128 * 32];
  const int m0 = blockIdx.x * 128;
  const int n0 = blockIdx.y * 128;
  const int tid = threadIdx.x;
  const int wave = tid >> 6, lane = tid & 63;
  const int wm = wave & 1, wn = wave >> 1;
  const int quad = lane >> 4, l16 = lane & 15;
  const int srow = lane >> 2, sch = lane & 3;

  f32x4 acc[4][4] = {};

  for (int k0 = 0; k0 < 2048; k0 += 32) {
#pragma unroll
    for (int s = 0; s < 2; ++s) {
      const int instr = wave * 2 + s;
      const int row = instr * 16 + srow;
      gload_lds16(A + (size_t)(m0 + row) * 2048 + k0 + sch * 8, (char*)sA + instr * 1024);
      gload_lds16(Bt + (size_t)(n0 + row) * 2048 + k0 + sch * 8, (char*)sB + instr * 1024);
    }
    __syncthreads();
    bf16x8 af[4], bfr[4];
#pragma unroll
    for (int mf = 0; mf < 4; ++mf)
      af[mf] = *(const bf16x8*)(sA + (wm * 64 + mf * 16 + l16) * 32 + quad * 8);
#pragma unroll
    for (int nf = 0; nf < 4; ++nf)
      bfr[nf] = *(const bf16x8*)(sB + (wn * 64 + nf * 16 + l16) * 32 + quad * 8);
#pragma unroll
    for (int mf = 0; mf < 4; ++mf)
#pragma unroll
      for (int nf = 0; nf < 4; ++nf)
        acc[mf][nf] = MFMA_BF16(af[mf], bfr[nf], acc[mf][nf]);
    __syncthreads();
  }

#pragma unroll
  for (int mf = 0; mf < 4; ++mf) {
    const int mm = m0 + wm * 64 + mf * 16 + quad * 4;
#pragma unroll
    for (int nf = 0; nf < 4; ++nf) {
      const int col = n0 + wn * 64 + nf * 16 + l16;
#pragma unroll
      for (int i = 0; i < 4; ++i) C[(size_t)(mm + i) * 2048 + col] = acc[mf][nf][i];
    }
  }
}

extern "C" void kernel_launch(void* const* d_in, const int* in_sizes, int n_in,
                              void* d_out, int out_size, void* d_ws, size_t ws_size,
                              hipStream_t stream) {
  (void)in_sizes; (void)n_in; (void)out_size; (void)ws_size;
  const float* x     = (const float*)d_in[0];
  const int*   posi  = (const int*)d_in[1];
  const float* w_q   = (const float*)d_in[3];
  const float* w_kv  = (const float*)d_in[4];
  const float* w_out = (const float*)d_in[5];
  float* out = (float*)d_out;

  u16* ws = (u16*)d_ws;
  u16* wqt   = ws;
  u16* wkvt  = ws + (size_t)4194304;
  u16* woutt = ws + (size_t)8388608;
  u16* qb    = ws + (size_t)12582912;
  u16* kb    = ws + (size_t)20971520;
  u16* vtb   = ws + (size_t)25165824;
  u16* encb  = ws + (size_t)29360128;
  u16* xb    = encb;  // alias: consumed by gemm_qkv before attn writes enc

  f32_to_bf16<<<8192, 256, 0, stream>>>(x, xb, 8388608);
  transpose_f32_bf16<<<dim3(4, 64, 16), dim3(32, 8, 1), 0, stream>>>(w_q, wqt, 2048, 128);
  transpose_f32_bf16<<<dim3(4, 64, 16), dim3(32, 8, 1), 0, stream>>>(w_kv, wkvt, 2048, 128);
  transpose_f32_bf16<<<dim3(64, 64, 1), dim3(32, 8, 1), 0, stream>>>(w_out, woutt, 2048, 2048);
  gemm_qkv<<<dim3(32, 32), 256, 0, stream>>>(xb, wqt, wkvt, qb, kb, vtb);
  rope_kernel<<<24576, 256, 0, stream>>>(qb, kb, posi);
  attn_fused<<<512, 256, 0, stream>>>(qb, kb, vtb, encb);
  gemm_out<<<dim3(32, 16), 256, 0, stream>>>(encb, woutt, out);
}

// Round 6
// 395.821 us; speedup vs baseline: 1.1522x; 1.0289x over previous
//
#include <hip/hip_runtime.h>
#include <math.h>
#include <stdint.h>

// Problem constants (B=2, T=2048, D=2048, N=16 q-heads, K=8 kv-heads, G=2, H=128)
// Inputs/outputs are FLOAT32; positions int32; mask bool (unused: causal).
// Internals bf16 (MFMA) with f32 accumulation.
//
// Workspace layout (u16 elements), total 75,497,472 bytes:
//   wqkv_t [32][128][2048]   @ 0              (bf16, transposed; 0..15 Q heads, 16..23 K, 24..31 V)
//   wout_t [2048][2048]      @ 8388608
//   q      [2][16][2048][128]@ 12582912       (roped+scaled, bf16)
//   k      [2][8][2048][128] @ 20971520       (roped, bf16)
//   vt     [2][8][128][2048] @ 25165824       (V transposed: [h][t], bf16)
//   enc    [2][2048][16][128]@ 29360128       (bf16) -- aliased as xb before attn

typedef unsigned short u16;
using bf16x8 = __attribute__((ext_vector_type(8))) short;
using f32x4  = __attribute__((ext_vector_type(4))) float;

#define MFMA_BF16(a,b,c) __builtin_amdgcn_mfma_f32_16x16x32_bf16((a),(b),(c),0,0,0)

static __device__ __forceinline__ float b2f(u16 u) {
  union { unsigned int i; float f; } v; v.i = ((unsigned int)u) << 16; return v.f;
}
static __device__ __forceinline__ u16 f2b(float f) {
  union { float f; unsigned int i; } v; v.f = f;
  unsigned int r = v.i + 0x7fffu + ((v.i >> 16) & 1u);
  return (u16)(r >> 16);
}
// pack two f32 -> bf16x2 dword (round-half-up; inputs are >= 0 softmax weights)
static __device__ __forceinline__ unsigned pk2(float x0, float x1) {
  union { float f; unsigned u; } a, b;
  a.f = x0; b.f = x1;
  return __builtin_amdgcn_perm(b.u + 0x8000u, a.u + 0x8000u, 0x07060302u);
}
static __device__ __forceinline__ void gload_lds16(const void* g, void* l) {
  __builtin_amdgcn_global_load_lds((__attribute__((address_space(1))) void*)(g),
                                   (__attribute__((address_space(3))) void*)(l),
                                   16, 0, 0);
}

// ---------------- prep: x f32->bf16 convert + all weight transposes, one launch ----------------
// blocks [0,8192): convert x (4 f32/thread)
// blocks [8192,12288): transpose w_q     16 x [2048][128] -> [128][2048]
// blocks [12288,16384): transpose w_kv   16 x [2048][128] -> [128][2048]
// blocks [16384,20480): transpose w_out  [2048][2048] -> [2048][2048]
__global__ __launch_bounds__(256) void prep(const float* __restrict__ x, u16* __restrict__ xb,
                                            const float* __restrict__ wq,
                                            const float* __restrict__ wkv,
                                            const float* __restrict__ wout,
                                            u16* __restrict__ wqkvt, u16* __restrict__ woutt) {
  const int tid = threadIdx.x;
  int bid = blockIdx.x;
  if (bid < 8192) {
    const int i = (bid * 256 + tid) * 4;
    const float4 v = *(const float4*)(x + i);
    ushort4 o;
    o.x = f2b(v.x); o.y = f2b(v.y); o.z = f2b(v.z); o.w = f2b(v.w);
    *(ushort4*)(xb + i) = o;
    return;
  }
  bid -= 8192;
  const float* src;
  u16* dst;
  int rows, cols, bx, by;
  if (bid < 8192) {  // wq / wkv: 16 mats each, rows=2048, cols=128, tiles 4 x 64
    const int seg = bid >> 12;              // 0 = wq, 1 = wkv
    const int r = bid & 4095;
    const int mat = r >> 8;
    bx = (r & 255) & 3;
    by = (r & 255) >> 2;
    rows = 2048; cols = 128;
    src = (seg ? wkv : wq) + (size_t)mat * 2048 * 128;
    dst = wqkvt + (size_t)(seg * 16 + mat) * 2048 * 128;
  } else {           // wout: [2048][2048], tiles 64 x 64
    const int r = bid - 8192;
    bx = r & 63;
    by = r >> 6;
    rows = 2048; cols = 2048;
    src = wout;
    dst = woutt;
  }
  __shared__ u16 tile[32][33];
  const int c0 = bx * 32, r0 = by * 32;
  const int tx = tid & 31, ty = tid >> 5;
#pragma unroll
  for (int j = 0; j < 4; ++j)
    tile[ty + j * 8][tx] = f2b(src[(size_t)(r0 + ty + j * 8) * cols + (c0 + tx)]);
  __syncthreads();
#pragma unroll
  for (int j = 0; j < 4; ++j)
    dst[(size_t)(c0 + ty + j * 8) * rows + (r0 + tx)] = tile[tx][ty + j * 8];
}

// ---------------- QKV projection GEMM (BK=64, swizzled staging) ----------------
// C[m][h] = sum_d X[m][d] * Wt[h][d].  LDS tiles [128][64] u16, 128B rows,
// 16B chunks stored at ch ^ (row&7) (swizzle applied on the global-source side
// because global_load_lds pins LDS slot = lane*16).
__global__ __launch_bounds__(256) void gemm_qkv(const u16* __restrict__ X,
                                                const u16* __restrict__ wqkvt,
                                                u16* __restrict__ qb,
                                                u16* __restrict__ kb,
                                                u16* __restrict__ vtb) {
  __shared__ __align__(16) u16 sA[128 * 64];
  __shared__ __align__(16) u16 sB[128 * 64];
  const int m0 = blockIdx.x * 128;
  const int ct = blockIdx.y;
  const u16* Bt = wqkvt + (size_t)ct * 128 * 2048;
  const int tid = threadIdx.x;
  const int wave = tid >> 6, lane = tid & 63;
  const int wm = wave & 1, wn = wave >> 1;
  const int quad = lane >> 4, l16 = lane & 15;
  const int srow = lane >> 3;                    // 0..7 within 8-row group
  const int sch = (lane & 7) ^ srow;             // swizzled 16B chunk 0..7

  f32x4 acc[4][4] = {};

  for (int k0 = 0; k0 < 2048; k0 += 64) {
#pragma unroll
    for (int s = 0; s < 4; ++s) {
      const int instr = wave * 4 + s;            // 0..15, each stages 8 rows
      const int row = instr * 8 + srow;
      gload_lds16(X + (size_t)(m0 + row) * 2048 + k0 + sch * 8, (char*)sA + instr * 1024);
      gload_lds16(Bt + (size_t)row * 2048 + k0 + sch * 8, (char*)sB + instr * 1024);
    }
    __syncthreads();
#pragma unroll
    for (int ks = 0; ks < 2; ++ks) {
      bf16x8 af[4], bfr[4];
#pragma unroll
      for (int mf = 0; mf < 4; ++mf) {
        const int R = wm * 64 + mf * 16 + l16;
        af[mf] = *(const bf16x8*)((char*)sA + R * 128 + (((ks * 4 + quad) ^ (R & 7)) << 4));
      }
#pragma unroll
      for (int nf = 0; nf < 4; ++nf) {
        const int R = wn * 64 + nf * 16 + l16;
        bfr[nf] = *(const bf16x8*)((char*)sB + R * 128 + (((ks * 4 + quad) ^ (R & 7)) << 4));
      }
#pragma unroll
      for (int mf = 0; mf < 4; ++mf)
#pragma unroll
        for (int nf = 0; nf < 4; ++nf)
          acc[mf][nf] = MFMA_BF16(af[mf], bfr[nf], acc[mf][nf]);
    }
    __syncthreads();
  }

  // epilogue: C/D layout row=(quad*4+i), col=l16
#pragma unroll
  for (int mf = 0; mf < 4; ++mf) {
    const int mm = m0 + wm * 64 + mf * 16 + quad * 4;
    const int b = mm >> 11;
    const int t = mm & 2047;
#pragma unroll
    for (int nf = 0; nf < 4; ++nf) {
      const int h = wn * 64 + nf * 16 + l16;
      if (ct < 16) {
        u16* d = qb + (((size_t)b * 16 + ct) * 2048 + t) * 128 + h;
#pragma unroll
        for (int i = 0; i < 4; ++i) d[(size_t)i * 128] = f2b(acc[mf][nf][i]);
      } else if (ct < 24) {
        u16* d = kb + (((size_t)b * 8 + (ct - 16)) * 2048 + t) * 128 + h;
#pragma unroll
        for (int i = 0; i < 4; ++i) d[(size_t)i * 128] = f2b(acc[mf][nf][i]);
      } else {
        u16* d = vtb + (((size_t)b * 8 + (ct - 24)) * 128 + h) * 2048 + t;
        uint2 pkv;
        pkv.x = (unsigned)f2b(acc[mf][nf][0]) | ((unsigned)f2b(acc[mf][nf][1]) << 16);
        pkv.y = (unsigned)f2b(acc[mf][nf][2]) | ((unsigned)f2b(acc[mf][nf][3]) << 16);
        *(uint2*)d = pkv;
      }
    }
  }
}

// ---------------- RoPE (in-place on q and k, bf16; 2 j's per thread) ----------------
__global__ __launch_bounds__(256) void rope_kernel(u16* __restrict__ qb,
                                                   u16* __restrict__ kb,
                                                   const int* __restrict__ pos) {
  const unsigned idx = blockIdx.x * 256 + threadIdx.x;
  const unsigned QP = 1u << 21;  // 2*16*2048*32
  u16* p;
  float scale;
  int b, t, j2;
  if (idx < QP) {
    j2 = (int)(idx & 31) * 2; t = (int)((idx >> 5) & 2047);
    const int hd = (int)((idx >> 16) & 15); b = (int)(idx >> 20);
    p = qb + (((size_t)b * 16 + hd) * 2048 + t) * 128;
    scale = 0.08838834764831845f;  // 1/sqrt(128)
  } else {
    const unsigned r = idx - QP;
    j2 = (int)(r & 31) * 2; t = (int)((r >> 5) & 2047);
    const int hd = (int)((r >> 16) & 7); b = (int)(r >> 19);
    p = kb + (((size_t)b * 8 + hd) * 2048 + t) * 128;
    scale = 1.0f;
  }
  const float fpos = (float)pos[(size_t)b * 2048 + t];
  const unsigned lo = *(const unsigned*)(p + j2);
  const unsigned hi = *(const unsigned*)(p + j2 + 64);
  unsigned olo = 0, ohi = 0;
#pragma unroll
  for (int d = 0; d < 2; ++d) {
    const int j = j2 + d;
    const float ts = __powf(10000.0f, (float)j * (1.0f / 64.0f));
    float sn, cs;
    sincosf(fpos / ts, &sn, &cs);
    const float a = b2f((u16)((d ? (lo >> 16) : lo) & 0xffffu));
    const float c2 = b2f((u16)((d ? (hi >> 16) : hi) & 0xffffu));
    olo |= ((unsigned)f2b((a * cs - c2 * sn) * scale)) << (16 * d);
    ohi |= ((unsigned)f2b((c2 * cs + a * sn) * scale)) << (16 * d);
  }
  *(unsigned*)(p + j2) = olo;
  *(unsigned*)(p + j2 + 64) = ohi;
}

// ---------------- fused causal attention, S^T formulation ----------------
// 512 blocks x 256 thr. Block = (head, pair p): pass A q-tile Q=p, pass B Q=31-p
// (perfectly balanced 33 s-iters/block, all blocks co-resident). Wave owns 16 t.
// Softcap bounds logits <=50 -> fixed-offset softmax (no max, no O-rescale).
__global__ __launch_bounds__(256) void attn_fused(const u16* __restrict__ qg,
                                                  const u16* __restrict__ kg,
                                                  const u16* __restrict__ vtg,
                                                  u16* __restrict__ enc) {
  __shared__ __align__(16) char lds[32768];
  char* sK = lds;            // [64 s][128 h] bf16, 16B chunks swizzled: ch ^ (row&15)
  char* sV = lds + 16384;    // [128 h][64 s] bf16, 16B chunks swizzled: ch ^ (row&7)

  const int bid = blockIdx.x;
  const int x = bid & 7;           // head % 8  -> XCD locality
  const int i6 = bid >> 3;
  const int p = i6 & 15;
  const int head = (i6 >> 4) * 8 + x;
  const int b = head >> 4;
  const int n = head & 15;
  const int kh = n >> 1;

  const u16* qbase = qg + ((size_t)b * 16 + n) * 2048 * 128;
  const u16* kbase = kg + ((size_t)b * 8 + kh) * 2048 * 128;
  const u16* vbase = vtg + ((size_t)b * 8 + kh) * 128 * 2048;

  const int tid = threadIdx.x, wave = tid >> 6, lane = tid & 63;
  const int quad = lane >> 4, l16 = lane & 15;
  const int bp_a0 = ((quad & 1) * 32 + l16) * 4;  // ds_bpermute byte idx, source lane S0
  const int bp_a1 = bp_a0 + 64;                   // source lane S1

  const float L2E = 1.4426950408889634f;
  const float C50 = 72.13475204444817f;  // 50 * log2(e)
  // 50*tanh(x/50) = x*(1 - a1*u + a2*u^2 - a3*u^3), u = x^2  (Taylor, |x|<~25)
  const float A1 = 1.3333333333e-4f;
  const float A2 = 2.1333333333e-8f;
  const float A3 = 3.4539682540e-12f;

#pragma unroll 1
  for (int pass = 0; pass < 2; ++pass) {
    const int Q = pass ? (31 - p) : p;
    const int tw = Q * 64 + wave * 16;   // wave's t = tw + l16
    const int tlane = tw + l16;

    // Q B-fragments (n = l16 = t, k contiguous)
    bf16x8 qf[4];
#pragma unroll
    for (int kf = 0; kf < 4; ++kf)
      qf[kf] = *(const bf16x8*)(qbase + (size_t)tlane * 128 + kf * 32 + quad * 8);

    f32x4 o[8] = {};
    f32x4 lacc = {0.f, 0.f, 0.f, 0.f};

#pragma unroll 1
    for (int si = 0; si <= Q; ++si) {
      const int s0 = si * 64;
      __syncthreads();
      // stage K (16KB) + V^T (16KB); coalesced float4 reads, swizzled LDS writes
#pragma unroll
      for (int r2 = 0; r2 < 4; ++r2) {
        const int idx = r2 * 256 + tid;
        const int kr = idx >> 4, kc = idx & 15;
        *(float4*)(sK + kr * 256 + ((kc ^ (kr & 15)) << 4)) =
            *(const float4*)(kbase + (size_t)(s0 + kr) * 128 + kc * 8);
        const int vr = idx >> 3, vc = idx & 7;
        *(float4*)(sV + vr * 128 + ((vc ^ (vr & 7)) << 4)) =
            *(const float4*)(vbase + (size_t)vr * 2048 + s0 + vc * 8);
      }
      __syncthreads();

      const bool diag = (si == Q);
      const int nfmax = diag ? wave : 3;        // skip fully-masked s-frags
      const int kmax = diag ? (wave >> 1) : 1;

      // S^T = K Q^T : A = K (m=s), B = Q (n=t). C: col=t=l16, row=s=quad*4+reg
      f32x4 sacc[4];
#pragma unroll
      for (int nf = 0; nf < 4; ++nf) {
        if (nf <= nfmax) {
          const int sr = nf * 16 + l16;
          f32x4 a = {0.f, 0.f, 0.f, 0.f};
#pragma unroll
          for (int kf = 0; kf < 4; ++kf) {
            const bf16x8 kfr =
                *(const bf16x8*)(sK + sr * 256 + (((kf * 4 + quad) ^ (sr & 15)) << 4));
            a = MFMA_BF16(kfr, qf[kf], a);
          }
          sacc[nf] = a;
        }
      }

      // poly softcap + fixed-offset exp (no max, no rescale) + mask + l accumulate
#pragma unroll
      for (int nf = 0; nf < 4; ++nf) {
        if (nf <= nfmax) {
          const f32x4 xv = sacc[nf];
          const f32x4 u = xv * xv;
          f32x4 t = u * (-A3) + A2;
          t = u * t + (-A1);
          t = u * t + 1.0f;
          const f32x4 tc = xv * t;          // 50*tanh(x/50), in [-50, 50]
          f32x4 pv;
#pragma unroll
          for (int i = 0; i < 4; ++i) pv[i] = exp2f(fmaf(tc[i], L2E, -C50));
          if (diag) {
#pragma unroll
            for (int i = 0; i < 4; ++i) {
              const int sg = s0 + nf * 16 + quad * 4 + i;
              if (sg > tlane) pv[i] = 0.0f;
            }
          }
          sacc[nf] = pv;
          lacc += pv;
        }
      }

      // pack P columns to bf16x2 dwords (per-lane)
      unsigned pkd[4][2];
#pragma unroll
      for (int nf = 0; nf < 4; ++nf) {
        if (nf <= nfmax) {
          pkd[nf][0] = pk2(sacc[nf][0], sacc[nf][1]);
          pkd[nf][1] = pk2(sacc[nf][2], sacc[nf][3]);
        } else {
          pkd[nf][0] = 0u; pkd[nf][1] = 0u;
        }
      }

      // O^T += V^T P^T : per chunk c2 (k = s 32-wide), build P^T B-frag via bpermute
#pragma unroll
      for (int c2 = 0; c2 < 2; ++c2) {
        if (c2 <= kmax) {
          const int lo = (quad >> 1);  // selects nf = 2*c2 + (quad>>1)
          const int dA0 = __builtin_amdgcn_ds_bpermute(bp_a0, (int)pkd[2 * c2][0]);
          const int dB0 = __builtin_amdgcn_ds_bpermute(bp_a0, (int)pkd[2 * c2 + 1][0]);
          const int dA1 = __builtin_amdgcn_ds_bpermute(bp_a0, (int)pkd[2 * c2][1]);
          const int dB1 = __builtin_amdgcn_ds_bpermute(bp_a0, (int)pkd[2 * c2 + 1][1]);
          const int dA2 = __builtin_amdgcn_ds_bpermute(bp_a1, (int)pkd[2 * c2][0]);
          const int dB2 = __builtin_amdgcn_ds_bpermute(bp_a1, (int)pkd[2 * c2 + 1][0]);
          const int dA3 = __builtin_amdgcn_ds_bpermute(bp_a1, (int)pkd[2 * c2][1]);
          const int dB3 = __builtin_amdgcn_ds_bpermute(bp_a1, (int)pkd[2 * c2 + 1][1]);
          union { int d[4]; bf16x8 v; } pb;
          pb.d[0] = lo ? dB0 : dA0;
          pb.d[1] = lo ? dB1 : dA1;
          pb.d[2] = lo ? dB2 : dA2;
          pb.d[3] = lo ? dB3 : dA3;
#pragma unroll
          for (int nfo = 0; nfo < 8; ++nfo) {
            const int hr = nfo * 16 + l16;
            const bf16x8 vb =
                *(const bf16x8*)(sV + hr * 128 + (((c2 * 4 + quad) ^ (hr & 7)) << 4));
            o[nfo] = MFMA_BF16(vb, pb.v, o[nfo]);
          }
        }
      }
    }

    // epilogue: reduce l across quads (same t = l16 in each 16-lane group)
    float lsum = lacc[0] + lacc[1] + lacc[2] + lacc[3];
    lsum += __shfl_xor(lsum, 16);
    lsum += __shfl_xor(lsum, 32);
    const float inv = 1.0f / lsum;
    u16* d = enc + (((size_t)b * 2048 + tlane) * 16 + n) * 128 + quad * 4;
#pragma unroll
    for (int nfo = 0; nfo < 8; ++nfo) {
      uint2 st;
      st.x = (unsigned)f2b(o[nfo][0] * inv) | ((unsigned)f2b(o[nfo][1] * inv) << 16);
      st.y = (unsigned)f2b(o[nfo][2] * inv) | ((unsigned)f2b(o[nfo][3] * inv) << 16);
      *(uint2*)(d + nfo * 16) = st;
    }
  }
}

// ---------------- output projection GEMM (BK=64, swizzled staging, f32 out) ----------------
__global__ __launch_bounds__(256) void gemm_out(const u16* __restrict__ A,
                                                const u16* __restrict__ Bt,
                                                float* __restrict__ C) {
  __shared__ __align__(16) u16 sA[128 * 64];
  __shared__ __align__(16) u16 sB[128 * 64];
  const int m0 = blockIdx.x * 128;
  const int n0 = blockIdx.y * 128;
  const int tid = threadIdx.x;
  const int wave = tid >> 6, lane = tid & 63;
  const int wm = wave & 1, wn = wave >> 1;
  const int quad = lane >> 4, l16 = lane & 15;
  const int srow = lane >> 3;
  const int sch = (lane & 7) ^ srow;

  f32x4 acc[4][4] = {};

  for (int k0 = 0; k0 < 2048; k0 += 64) {
#pragma unroll
    for (int s = 0; s < 4; ++s) {
      const int instr = wave * 4 + s;
      const int row = instr * 8 + srow;
      gload_lds16(A + (size_t)(m0 + row) * 2048 + k0 + sch * 8, (char*)sA + instr * 1024);
      gload_lds16(Bt + (size_t)(n0 + row) * 2048 + k0 + sch * 8, (char*)sB + instr * 1024);
    }
    __syncthreads();
#pragma unroll
    for (int ks = 0; ks < 2; ++ks) {
      bf16x8 af[4], bfr[4];
#pragma unroll
      for (int mf = 0; mf < 4; ++mf) {
        const int R = wm * 64 + mf * 16 + l16;
        af[mf] = *(const bf16x8*)((char*)sA + R * 128 + (((ks * 4 + quad) ^ (R & 7)) << 4));
      }
#pragma unroll
      for (int nf = 0; nf < 4; ++nf) {
        const int R = wn * 64 + nf * 16 + l16;
        bfr[nf] = *(const bf16x8*)((char*)sB + R * 128 + (((ks * 4 + quad) ^ (R & 7)) << 4));
      }
#pragma unroll
      for (int mf = 0; mf < 4; ++mf)
#pragma unroll
        for (int nf = 0; nf < 4; ++nf)
          acc[mf][nf] = MFMA_BF16(af[mf], bfr[nf], acc[mf][nf]);
    }
    __syncthreads();
  }

#pragma unroll
  for (int mf = 0; mf < 4; ++mf) {
    const int mm = m0 + wm * 64 + mf * 16 + quad * 4;
#pragma unroll
    for (int nf = 0; nf < 4; ++nf) {
      const int col = n0 + wn * 64 + nf * 16 + l16;
#pragma unroll
      for (int i = 0; i < 4; ++i) C[(size_t)(mm + i) * 2048 + col] = acc[mf][nf][i];
    }
  }
}

extern "C" void kernel_launch(void* const* d_in, const int* in_sizes, int n_in,
                              void* d_out, int out_size, void* d_ws, size_t ws_size,
                              hipStream_t stream) {
  (void)in_sizes; (void)n_in; (void)out_size; (void)ws_size;
  const float* x     = (const float*)d_in[0];
  const int*   posi  = (const int*)d_in[1];
  const float* w_q   = (const float*)d_in[3];
  const float* w_kv  = (const float*)d_in[4];
  const float* w_out = (const float*)d_in[5];
  float* out = (float*)d_out;

  u16* ws = (u16*)d_ws;
  u16* wqkvt = ws;
  u16* woutt = ws + (size_t)8388608;
  u16* qb    = ws + (size_t)12582912;
  u16* kb    = ws + (size_t)20971520;
  u16* vtb   = ws + (size_t)25165824;
  u16* encb  = ws + (size_t)29360128;
  u16* xb    = encb;  // alias: consumed by gemm_qkv before attn writes enc

  prep<<<20480, 256, 0, stream>>>(x, xb, w_q, w_kv, w_out, wqkvt, woutt);
  gemm_qkv<<<dim3(32, 32), 256, 0, stream>>>(xb, wqkvt, qb, kb, vtb);
  rope_kernel<<<12288, 256, 0, stream>>>(qb, kb, posi);
  attn_fused<<<512, 256, 0, stream>>>(qb, kb, vtb, encb);
  gemm_out<<<dim3(32, 16), 256, 0, stream>>>(encb, woutt, out);
}